// Round 2
// baseline (306.300 us; speedup 1.0000x reference)
//
#include <hip/hip_runtime.h>
#include <hip/hip_bf16.h>

constexpr int S_ = 4096;
constexpr int D_ = 512;

using f32x4 = __attribute__((ext_vector_type(4))) float;
using s16x8 = __attribute__((ext_vector_type(8))) short;
using u16x4 = __attribute__((ext_vector_type(4))) unsigned short;
using u16x8 = __attribute__((ext_vector_type(8))) unsigned short;

__device__ __forceinline__ unsigned short f2bf(float f) {
    union { float f; unsigned u; } v; v.f = f;
    unsigned r = v.u + 0x7FFFu + ((v.u >> 16) & 1u);
    return (unsigned short)(r >> 16);
}

__device__ __forceinline__ unsigned pack_bf16(float lo, float hi) {
    float2 t; t.x = lo; t.y = hi;
    __hip_bfloat162 b = __float22bfloat162_rn(t);
    union { __hip_bfloat162 b; unsigned u; } cv; cv.b = b; return cv.u;
}

// Y[M=4096][N=512] = X[M][512] @ W[N][512]^T
// OUT_MODE: 0 = bf16 row-major, 1 = bf16 transposed ([N][S_]), 2 = fp32 row-major
template<bool IN_BF16, int OUT_MODE>
__global__ __launch_bounds__(256) void proj_kernel(const void* __restrict__ Xv,
                                                   const float* __restrict__ W,
                                                   void* __restrict__ Yv) {
    constexpr int BM = 128, BN = 64, BK = 64;
    __shared__ unsigned short Xs[BM][BK + 8];
    __shared__ unsigned short Ws_[BN][BK + 8];
    const int m0 = blockIdx.x * BM;
    const int n0 = blockIdx.y * BN;
    const int tid = threadIdx.x;
    const int lane = tid & 63, w = tid >> 6;
    const int wi = w >> 1, wj = w & 1;
    const int lr = lane & 15, lg = lane >> 4;

    f32x4 acc[4][2] = {};

    for (int kt = 0; kt < D_ / BK; ++kt) {
        const int k0 = kt * BK;
        __syncthreads();
        if (IN_BF16) {
            const unsigned short* X = (const unsigned short*)Xv;
#pragma unroll
            for (int r = 0; r < 4; ++r) {
                int idx = tid + r * 256;
                int row = idx >> 3, c8 = idx & 7;
                u16x8 vv = *(const u16x8*)(X + (size_t)(m0 + row) * D_ + k0 + c8 * 8);
                *(u16x8*)&Xs[row][c8 * 8] = vv;
            }
        } else {
            const float* X = (const float*)Xv;
#pragma unroll
            for (int r = 0; r < 8; ++r) {
                int idx = tid + r * 256;
                int row = idx >> 4, c4 = idx & 15;
                f32x4 vv = *(const f32x4*)(X + (size_t)(m0 + row) * D_ + k0 + c4 * 4);
                u16x4 o;
#pragma unroll
                for (int t = 0; t < 4; ++t) o[t] = f2bf(vv[t]);
                *(u16x4*)&Xs[row][c4 * 4] = o;
            }
        }
#pragma unroll
        for (int r = 0; r < 4; ++r) {
            int idx = tid + r * 256;
            int row = idx >> 4, c4 = idx & 15;
            f32x4 vv = *(const f32x4*)(W + (size_t)(n0 + row) * D_ + k0 + c4 * 4);
            u16x4 o;
#pragma unroll
            for (int t = 0; t < 4; ++t) o[t] = f2bf(vv[t]);
            *(u16x4*)&Ws_[row][c4 * 4] = o;
        }
        __syncthreads();
#pragma unroll
        for (int ks = 0; ks < 2; ++ks) {
            s16x8 a[4], b[2];
#pragma unroll
            for (int mf = 0; mf < 4; ++mf)
                a[mf] = *(const s16x8*)&Xs[wi * 64 + mf * 16 + lr][ks * 32 + lg * 8];
#pragma unroll
            for (int nf = 0; nf < 2; ++nf)
                b[nf] = *(const s16x8*)&Ws_[wj * 32 + nf * 16 + lr][ks * 32 + lg * 8];
#pragma unroll
            for (int mf = 0; mf < 4; ++mf)
#pragma unroll
                for (int nf = 0; nf < 2; ++nf)
                    acc[mf][nf] = __builtin_amdgcn_mfma_f32_16x16x32_bf16(a[mf], b[nf], acc[mf][nf], 0, 0, 0);
        }
    }

    if (OUT_MODE == 1) {
        __syncthreads();
        unsigned short* T = &Xs[0][0] + w * 2304;   // per-wave [32][72]
#pragma unroll
        for (int mf = 0; mf < 4; ++mf)
#pragma unroll
            for (int nf = 0; nf < 2; ++nf)
#pragma unroll
                for (int r = 0; r < 4; ++r) {
                    int n_loc = nf * 16 + lr;
                    int i_loc = mf * 16 + lg * 4 + r;
                    T[n_loc * 72 + i_loc] = f2bf(acc[mf][nf][r]);
                }
        __syncthreads();
        unsigned short* Y = (unsigned short*)Yv;
#pragma unroll
        for (int rr = 0; rr < 4; ++rr) {
            int chunk = lane + rr * 64;
            int n_loc = chunk >> 3, c8 = chunk & 7;
            u16x8 vv = *(const u16x8*)&T[n_loc * 72 + c8 * 8];
            *(u16x8*)(Y + (size_t)(n0 + wj * 32 + n_loc) * S_ + m0 + wi * 64 + c8 * 8) = vv;
        }
    } else {
#pragma unroll
        for (int mf = 0; mf < 4; ++mf)
#pragma unroll
            for (int nf = 0; nf < 2; ++nf)
#pragma unroll
                for (int r = 0; r < 4; ++r) {
                    int i = m0 + wi * 64 + mf * 16 + lg * 4 + r;
                    int n = n0 + wj * 32 + nf * 16 + lr;
                    float val = acc[mf][nf][r];
                    if (OUT_MODE == 0) ((unsigned short*)Yv)[(size_t)i * D_ + n] = f2bf(val);
                    else                ((float*)Yv)[(size_t)i * D_ + n] = val;
                }
    }
}

// Attention, head-axis softmax. Block = 16 q-rows, 128 threads (2 waves).
// Wave w owns j-half (16 of 32) for QK^T (all 8 heads, swapped mfma(K,Q)),
// softmax lane-local, packed 8B P-writes to Es; PV: wave w owns heads 4w..4w+3.
__global__ __launch_bounds__(128, 3) void attn_kernel(const unsigned short* __restrict__ Qp,
                                                      const unsigned short* __restrict__ Kp,
                                                      const unsigned short* __restrict__ VpT,
                                                      float* __restrict__ partial, int njc) {
    __shared__ unsigned char Qlds[16 * 1024];      // [16 rows][1024B], XOR-swizzled
    __shared__ unsigned short Es[8][16][40];       // normalized P, [h][i][j], row 80B
    const int i0 = blockIdx.x * 16;
    const int jc = blockIdx.y;
    const int tid = threadIdx.x;
    const int lane = tid & 63, w = tid >> 6;
    const int lr = lane & 15, lg = lane >> 4;

#pragma unroll
    for (int r = 0; r < 8; ++r) {                  // stage Q 16x512 bf16, swizzled
        int idx = tid + r * 128;                   // 1024 chunks of 16B
        int row = idx >> 6, c16 = idx & 63;
        u16x8 vv = *(const u16x8*)(Qp + (size_t)(i0 + row) * D_ + c16 * 8);
        *(u16x8*)&Qlds[row * 1024 + ((c16 * 16) ^ ((row & 7) << 4))] = vv;
    }
    __syncthreads();

    f32x4 acc[4][4] = {};                          // [head-of-4][dfrag]
    const int t0 = (jc * 128) / njc;
    const int t1 = ((jc + 1) * 128) / njc;

    for (int t = t0; t < t1; ++t) {
        const int jq = t * 32 + w * 16;            // this wave's 16 j rows for QK
        // ---- QK^T swapped: S[h][i=lr][j=jq+lg*4+r] ----
        f32x4 sf[8];
#pragma unroll
        for (int h = 0; h < 8; ++h) {
            f32x4 s = {0.f, 0.f, 0.f, 0.f};
#pragma unroll
            for (int ks = 0; ks < 2; ++ks) {
                s16x8 a = *(const s16x8*)(Kp + (size_t)(jq + lr) * D_ + h * 64 + ks * 32 + lg * 8);
                s16x8 b = *(const s16x8*)&Qlds[lr * 1024 +
                              (((h * 128 + ks * 64 + lg * 16)) ^ ((lr & 7) << 4))];
                s = __builtin_amdgcn_mfma_f32_16x16x32_bf16(a, b, s, 0, 0, 0);
            }
            sf[h] = s;
        }
        // ---- head-softmax (lane-local), pack to bf16 pairs ----
        float p[8][4];
#pragma unroll
        for (int r = 0; r < 4; ++r) {
            float e[8], den = 0.f;
#pragma unroll
            for (int h = 0; h < 8; ++h) { e[h] = __expf(sf[h][r] * 0.125f); den += e[h]; }
            float rd = __builtin_amdgcn_rcpf(den);
#pragma unroll
            for (int h = 0; h < 8; ++h) p[h][r] = e[h] * rd;
        }
        __syncthreads();                           // prev-tile PV reads of Es done
#pragma unroll
        for (int h = 0; h < 8; ++h) {
            uint2 d;
            d.x = pack_bf16(p[h][0], p[h][1]);
            d.y = pack_bf16(p[h][2], p[h][3]);
            *(uint2*)&Es[h][lr][w * 16 + lg * 4] = d;
        }
        __syncthreads();                           // Es visible
        // ---- PV: heads 4w..4w+3, K=32 over this tile's 32 j ----
        const int jt = t * 32;
#pragma unroll
        for (int hh = 0; hh < 4; ++hh) {
            int h = w * 4 + hh;
            s16x8 pa = *(const s16x8*)&Es[h][lr][lg * 8];
#pragma unroll
            for (int df = 0; df < 4; ++df) {
                s16x8 b = *(const s16x8*)(VpT + (size_t)(h * 64 + df * 16 + lr) * S_ + jt + lg * 8);
                acc[hh][df] = __builtin_amdgcn_mfma_f32_16x16x32_bf16(pa, b, acc[hh][df], 0, 0, 0);
            }
        }
    }

    float* P = partial + (size_t)jc * S_ * D_;
#pragma unroll
    for (int hh = 0; hh < 4; ++hh) {
        int h = w * 4 + hh;
#pragma unroll
        for (int df = 0; df < 4; ++df)
#pragma unroll
            for (int r = 0; r < 4; ++r) {
                int i = i0 + lg * 4 + r;
                int d = h * 64 + df * 16 + lr;
                P[(size_t)i * D_ + d] = acc[hh][df][r];
            }
    }
}

__global__ __launch_bounds__(256) void reduceN_kernel(const float* __restrict__ partial,
                                                      unsigned short* __restrict__ outp, int njc) {
    size_t base = ((size_t)blockIdx.x * 256 + threadIdx.x) * 4;
    f32x4 s = *(const f32x4*)(partial + base);
    for (int c = 1; c < njc; ++c) {
        f32x4 vv = *(const f32x4*)(partial + (size_t)c * S_ * D_ + base);
        s += vv;
    }
    u16x4 o;
#pragma unroll
    for (int t = 0; t < 4; ++t) o[t] = f2bf(s[t]);
    *(u16x4*)(outp + base) = o;
}

extern "C" void kernel_launch(void* const* d_in, const int* in_sizes, int n_in,
                              void* d_out, int out_size, void* d_ws, size_t ws_size,
                              hipStream_t stream) {
    const float* q  = (const float*)d_in[0];
    const float* k  = (const float*)d_in[1];
    const float* v  = (const float*)d_in[2];
    const float* Wq = (const float*)d_in[3];
    const float* Wk = (const float*)d_in[4];
    const float* Wv = (const float*)d_in[5];
    const float* Wo = (const float*)d_in[6];

    // pick j-chunk count by available workspace: need 16MB + njc*8MB
    int njc = 2;
    if      (ws_size >= ((size_t)(16 + 8 * 6) << 20)) njc = 6;   // 1536 blocks = 6/CU exactly
    else if (ws_size >= ((size_t)(16 + 8 * 4) << 20)) njc = 4;

    char* ws = (char*)d_ws;
    unsigned short* Qp  = (unsigned short*)(ws);                    // 4 MB bf16 [S][D]
    unsigned short* Kp  = (unsigned short*)(ws + (4u  << 20));      // 4 MB bf16 [S][D]
    unsigned short* VpT = (unsigned short*)(ws + (8u  << 20));      // 4 MB bf16 [D][S]
    float*          part= (float*)        (ws + (12u << 20));       // njc * 8 MB fp32
    unsigned short* ao  = (unsigned short*)(ws + ((size_t)(12 + 8 * njc) << 20)); // 4 MB bf16

    dim3 pb(256);
    dim3 pg(S_ / 128, D_ / 64);
    proj_kernel<false, 0><<<pg, pb, 0, stream>>>(q, Wq, Qp);
    proj_kernel<false, 0><<<pg, pb, 0, stream>>>(k, Wk, Kp);
    proj_kernel<false, 1><<<pg, pb, 0, stream>>>(v, Wv, VpT);
    attn_kernel<<<dim3(S_ / 16, njc), dim3(128), 0, stream>>>(Qp, Kp, VpT, part, njc);
    reduceN_kernel<<<dim3(S_ * D_ / 1024), pb, 0, stream>>>(part, ao, njc);
    proj_kernel<true, 2><<<pg, pb, 0, stream>>>(ao, Wo, (float*)d_out);
}

// Round 4
// 242.449 us; speedup vs baseline: 1.2634x; 1.2634x over previous
//
#include <hip/hip_runtime.h>
#include <hip/hip_bf16.h>

constexpr int S_ = 4096;
constexpr int D_ = 512;

using f32x4 = __attribute__((ext_vector_type(4))) float;
using s16x8 = __attribute__((ext_vector_type(8))) short;
using u16x4 = __attribute__((ext_vector_type(4))) unsigned short;
using u16x8 = __attribute__((ext_vector_type(8))) unsigned short;

__device__ __forceinline__ unsigned short f2bf(float f) {
    union { float f; unsigned u; } v; v.f = f;
    unsigned r = v.u + 0x7FFFu + ((v.u >> 16) & 1u);
    return (unsigned short)(r >> 16);
}

__device__ __forceinline__ unsigned pack_bf16(float lo, float hi) {
    float2 t; t.x = lo; t.y = hi;
    __hip_bfloat162 b = __float22bfloat162_rn(t);
    union { __hip_bfloat162 b; unsigned u; } cv; cv.b = b; return cv.u;
}

// Y[M=4096][N=512] = (X[M][512] @ W[N][512]^T) * scale
// OUT_MODE: 0 = bf16 row-major, 1 = bf16 transposed ([N][S_]), 2 = fp32 row-major
template<bool IN_BF16, int OUT_MODE>
__global__ __launch_bounds__(256) void proj_kernel(const void* __restrict__ Xv,
                                                   const float* __restrict__ W,
                                                   void* __restrict__ Yv, float scale) {
    constexpr int BM = 128, BN = 64, BK = 64;
    __shared__ unsigned short Xs[BM][BK + 8];
    __shared__ unsigned short Ws_[BN][BK + 8];
    const int m0 = blockIdx.x * BM;
    const int n0 = blockIdx.y * BN;
    const int tid = threadIdx.x;
    const int lane = tid & 63, w = tid >> 6;
    const int wi = w >> 1, wj = w & 1;
    const int lr = lane & 15, lg = lane >> 4;

    f32x4 acc[4][2] = {};

    for (int kt = 0; kt < D_ / BK; ++kt) {
        const int k0 = kt * BK;
        __syncthreads();
        if (IN_BF16) {
            const unsigned short* X = (const unsigned short*)Xv;
#pragma unroll
            for (int r = 0; r < 4; ++r) {
                int idx = tid + r * 256;
                int row = idx >> 3, c8 = idx & 7;
                u16x8 vv = *(const u16x8*)(X + (size_t)(m0 + row) * D_ + k0 + c8 * 8);
                *(u16x8*)&Xs[row][c8 * 8] = vv;
            }
        } else {
            const float* X = (const float*)Xv;
#pragma unroll
            for (int r = 0; r < 8; ++r) {
                int idx = tid + r * 256;
                int row = idx >> 4, c4 = idx & 15;
                f32x4 vv = *(const f32x4*)(X + (size_t)(m0 + row) * D_ + k0 + c4 * 4);
                u16x4 o;
#pragma unroll
                for (int t = 0; t < 4; ++t) o[t] = f2bf(vv[t]);
                *(u16x4*)&Xs[row][c4 * 4] = o;
            }
        }
#pragma unroll
        for (int r = 0; r < 4; ++r) {
            int idx = tid + r * 256;
            int row = idx >> 4, c4 = idx & 15;
            f32x4 vv = *(const f32x4*)(W + (size_t)(n0 + row) * D_ + k0 + c4 * 4);
            u16x4 o;
#pragma unroll
            for (int t = 0; t < 4; ++t) o[t] = f2bf(vv[t]);
            *(u16x4*)&Ws_[row][c4 * 4] = o;
        }
        __syncthreads();
#pragma unroll
        for (int ks = 0; ks < 2; ++ks) {
            s16x8 a[4], b[2];
#pragma unroll
            for (int mf = 0; mf < 4; ++mf)
                a[mf] = *(const s16x8*)&Xs[wi * 64 + mf * 16 + lr][ks * 32 + lg * 8];
#pragma unroll
            for (int nf = 0; nf < 2; ++nf)
                b[nf] = *(const s16x8*)&Ws_[wj * 32 + nf * 16 + lr][ks * 32 + lg * 8];
#pragma unroll
            for (int mf = 0; mf < 4; ++mf)
#pragma unroll
                for (int nf = 0; nf < 2; ++nf)
                    acc[mf][nf] = __builtin_amdgcn_mfma_f32_16x16x32_bf16(a[mf], b[nf], acc[mf][nf], 0, 0, 0);
        }
    }

    if (OUT_MODE == 1) {
        __syncthreads();
        unsigned short* T = &Xs[0][0] + w * 2304;   // per-wave [32][72]
#pragma unroll
        for (int mf = 0; mf < 4; ++mf)
#pragma unroll
            for (int nf = 0; nf < 2; ++nf)
#pragma unroll
                for (int r = 0; r < 4; ++r) {
                    int n_loc = nf * 16 + lr;
                    int i_loc = mf * 16 + lg * 4 + r;
                    T[n_loc * 72 + i_loc] = f2bf(acc[mf][nf][r] * scale);
                }
        __syncthreads();
        unsigned short* Y = (unsigned short*)Yv;
#pragma unroll
        for (int rr = 0; rr < 4; ++rr) {
            int chunk = lane + rr * 64;
            int n_loc = chunk >> 3, c8 = chunk & 7;
            u16x8 vv = *(const u16x8*)&T[n_loc * 72 + c8 * 8];
            *(u16x8*)(Y + (size_t)(n0 + wj * 32 + n_loc) * S_ + m0 + wi * 64 + c8 * 8) = vv;
        }
    } else {
#pragma unroll
        for (int mf = 0; mf < 4; ++mf)
#pragma unroll
            for (int nf = 0; nf < 2; ++nf)
#pragma unroll
                for (int r = 0; r < 4; ++r) {
                    int i = m0 + wi * 64 + mf * 16 + lg * 4 + r;
                    int n = n0 + wj * 32 + nf * 16 + lr;
                    float val = acc[mf][nf][r] * scale;
                    if (OUT_MODE == 0) ((unsigned short*)Yv)[(size_t)i * D_ + n] = f2bf(val);
                    else                ((float*)Yv)[(size_t)i * D_ + n] = val;
                }
    }
}

// Attention, head-axis softmax. Block = 32 q-rows, 256 threads (4 waves).
// Swapped QK (mfma(K,Q)) -> lane-local softmax -> packed uint2 Es writes.
// PV: wave owns heads 2w,2w+1; V prefetched to regs before the barriers.
// Q pre-scaled by 0.125*log2(e) at projection -> p = 2^sf.
__global__ __launch_bounds__(256, 3) void attn_kernel(const unsigned short* __restrict__ Qp,
                                                      const unsigned short* __restrict__ Kp,
                                                      const unsigned short* __restrict__ VpT,
                                                      float* __restrict__ partial, int njc) {
    __shared__ unsigned char Qlds[32 * 1024];      // 32 rows x 1024B, XOR-swizzled
    __shared__ unsigned short Es[8][32][40];       // normalized P, [h][i][j], row 80B
    const int nblk = gridDim.x;                    // 128*njc, divisible by 8
    const int cpx = nblk >> 3;
    const int bid = blockIdx.x;
    const int rank = (bid & 7) * cpx + (bid >> 3); // jc-major clustering per XCD
    const int jc = rank >> 7;                      // rank / 128
    const int i0 = (rank & 127) * 32;
    const int tid = threadIdx.x;
    const int lane = tid & 63, w = tid >> 6;
    const int lr = lane & 15, lg = lane >> 4;
    const int wi = w >> 1, wj = w & 1;

#pragma unroll
    for (int r = 0; r < 8; ++r) {                  // stage Q 32x512 bf16, swizzled
        int idx = tid + r * 256;
        int row = idx >> 6, c16 = idx & 63;
        u16x8 vv = *(const u16x8*)(Qp + (size_t)(i0 + row) * D_ + c16 * 8);
        *(u16x8*)&Qlds[row * 1024 + ((c16 * 16) ^ ((row & 7) << 4))] = vv;
    }
    __syncthreads();

    f32x4 acc[2][2][4] = {};                       // [hh][mf][df]
    const int t0 = (jc * 128) / njc;
    const int t1 = ((jc + 1) * 128) / njc;

    for (int t = t0; t < t1; ++t) {
        const int j0 = t * 32;
        // ---- QK^T swapped: lane holds S[h][j=wj*16+lg*4+r][i=wi*16+lr] ----
        f32x4 sf[8];
#pragma unroll
        for (int h = 0; h < 8; ++h) {
            f32x4 s = {0.f, 0.f, 0.f, 0.f};
#pragma unroll
            for (int ks = 0; ks < 2; ++ks) {
                s16x8 a = *(const s16x8*)(Kp + (size_t)(j0 + wj * 16 + lr) * D_ + h * 64 + ks * 32 + lg * 8);
                s16x8 b = *(const s16x8*)&Qlds[(wi * 16 + lr) * 1024 +
                              ((h * 128 + ks * 64 + lg * 16) ^ ((lr & 7) << 4))];
                s = __builtin_amdgcn_mfma_f32_16x16x32_bf16(a, b, s, 0, 0, 0);
            }
            sf[h] = s;
        }
        // ---- V prefetch for this tile (used after barriers) ----
        s16x8 vb[2][4];
#pragma unroll
        for (int hh = 0; hh < 2; ++hh) {
            int h = 2 * w + hh;
#pragma unroll
            for (int df = 0; df < 4; ++df)
                vb[hh][df] = *(const s16x8*)(VpT + (size_t)(h * 64 + df * 16 + lr) * S_ + j0 + lg * 8);
        }
        // ---- head-softmax, lane-local: p = 2^sf / sum_h 2^sf ----
        float den[4] = {0.f, 0.f, 0.f, 0.f};
#pragma unroll
        for (int h = 0; h < 8; ++h)
#pragma unroll
            for (int r = 0; r < 4; ++r) { sf[h][r] = exp2f(sf[h][r]); den[r] += sf[h][r]; }
        float rd[4];
#pragma unroll
        for (int r = 0; r < 4; ++r) rd[r] = __builtin_amdgcn_rcpf(den[r]);
        __syncthreads();                           // prev-tile PV reads of Es done
#pragma unroll
        for (int h = 0; h < 8; ++h) {
            uint2 dw;
            dw.x = pack_bf16(sf[h][0] * rd[0], sf[h][1] * rd[1]);
            dw.y = pack_bf16(sf[h][2] * rd[2], sf[h][3] * rd[3]);
            *(uint2*)&Es[h][wi * 16 + lr][wj * 16 + lg * 4] = dw;
        }
        __syncthreads();                           // Es visible
        // ---- PV: heads 2w, 2w+1 ----
#pragma unroll
        for (int hh = 0; hh < 2; ++hh) {
            int h = 2 * w + hh;
#pragma unroll
            for (int mf = 0; mf < 2; ++mf) {
                s16x8 pa = *(const s16x8*)&Es[h][mf * 16 + lr][lg * 8];
#pragma unroll
                for (int df = 0; df < 4; ++df)
                    acc[hh][mf][df] = __builtin_amdgcn_mfma_f32_16x16x32_bf16(pa, vb[hh][df], acc[hh][mf][df], 0, 0, 0);
            }
        }
    }

    float* P = partial + (size_t)jc * S_ * D_;
#pragma unroll
    for (int hh = 0; hh < 2; ++hh) {
        int h = 2 * w + hh;
#pragma unroll
        for (int mf = 0; mf < 2; ++mf)
#pragma unroll
            for (int df = 0; df < 4; ++df)
#pragma unroll
                for (int r = 0; r < 4; ++r) {
                    int i = i0 + mf * 16 + lg * 4 + r;
                    int d = h * 64 + df * 16 + lr;
                    P[(size_t)i * D_ + d] = acc[hh][mf][df][r];
                }
    }
}

__global__ __launch_bounds__(256) void reduceN_kernel(const float* __restrict__ partial,
                                                      unsigned short* __restrict__ outp, int njc) {
    size_t base = ((size_t)blockIdx.x * 256 + threadIdx.x) * 4;
    f32x4 s = *(const f32x4*)(partial + base);
    for (int c = 1; c < njc; ++c) {
        f32x4 vv = *(const f32x4*)(partial + (size_t)c * S_ * D_ + base);
        s += vv;
    }
    u16x4 o;
#pragma unroll
    for (int t = 0; t < 4; ++t) o[t] = f2bf(s[t]);
    *(u16x4*)(outp + base) = o;
}

extern "C" void kernel_launch(void* const* d_in, const int* in_sizes, int n_in,
                              void* d_out, int out_size, void* d_ws, size_t ws_size,
                              hipStream_t stream) {
    const float* q  = (const float*)d_in[0];
    const float* k  = (const float*)d_in[1];
    const float* v  = (const float*)d_in[2];
    const float* Wq = (const float*)d_in[3];
    const float* Wk = (const float*)d_in[4];
    const float* Wv = (const float*)d_in[5];
    const float* Wo = (const float*)d_in[6];

    // workspace: 12MB (Qp,Kp,VpT) + njc*8MB (partial) + 4MB (ao)
    int njc = 2;
    if      (ws_size >= ((size_t)(16 + 8 * 6) << 20)) njc = 6;   // 768 blocks = 3/CU
    else if (ws_size >= ((size_t)(16 + 8 * 4) << 20)) njc = 4;

    char* ws = (char*)d_ws;
    unsigned short* Qp  = (unsigned short*)(ws);                    // 4 MB bf16 [S][D]
    unsigned short* Kp  = (unsigned short*)(ws + (4u  << 20));      // 4 MB bf16 [S][D]
    unsigned short* VpT = (unsigned short*)(ws + (8u  << 20));      // 4 MB bf16 [D][S]
    float*          part= (float*)        (ws + (12u << 20));       // njc * 8 MB fp32
    unsigned short* ao  = (unsigned short*)(ws + ((size_t)(12 + 8 * njc) << 20)); // 4 MB bf16

    const float qscale = 0.125f * 1.44269504088896340736f;  // 1/8 * log2(e)

    dim3 pb(256);
    dim3 pg(S_ / 128, D_ / 64);
    proj_kernel<false, 0><<<pg, pb, 0, stream>>>(q, Wq, Qp, qscale);
    proj_kernel<false, 0><<<pg, pb, 0, stream>>>(k, Wk, Kp, 1.0f);
    proj_kernel<false, 1><<<pg, pb, 0, stream>>>(v, Wv, VpT, 1.0f);
    attn_kernel<<<dim3(128 * njc), pb, 0, stream>>>(Qp, Kp, VpT, part, njc);
    reduceN_kernel<<<dim3(S_ * D_ / 1024), pb, 0, stream>>>(part, ao, njc);
    proj_kernel<true, 2><<<pg, pb, 0, stream>>>(ao, Wo, (float*)d_out, 1.0f);
}

// Round 5
// 234.540 us; speedup vs baseline: 1.3060x; 1.0337x over previous
//
#include <hip/hip_runtime.h>
#include <hip/hip_bf16.h>

constexpr int S_ = 4096;
constexpr int D_ = 512;
constexpr int NJC = 4;

using f32x4 = __attribute__((ext_vector_type(4))) float;
using s16x4 = __attribute__((ext_vector_type(4))) short;
using s16x8 = __attribute__((ext_vector_type(8))) short;
using u16x4 = __attribute__((ext_vector_type(4))) unsigned short;
using u16x8 = __attribute__((ext_vector_type(8))) unsigned short;

__device__ __forceinline__ unsigned short f2bf(float f) {
    union { float f; unsigned u; } v; v.f = f;
    unsigned r = v.u + 0x7FFFu + ((v.u >> 16) & 1u);
    return (unsigned short)(r >> 16);
}

__device__ __forceinline__ unsigned pack_bf16(float lo, float hi) {
    float2 t; t.x = lo; t.y = hi;
    __hip_bfloat162 b = __float22bfloat162_rn(t);
    union { __hip_bfloat162 b; unsigned u; } cv; cv.b = b; return cv.u;
}

__device__ __forceinline__ f32x4 mfma16(s16x4 a, s16x4 b, f32x4 c) {
#if __has_builtin(__builtin_amdgcn_mfma_f32_16x16x16bf16_1k)
    return __builtin_amdgcn_mfma_f32_16x16x16bf16_1k(a, b, c, 0, 0, 0);
#elif __has_builtin(__builtin_amdgcn_mfma_f32_16x16x16_bf16)
    return __builtin_amdgcn_mfma_f32_16x16x16_bf16(a, b, c, 0, 0, 0);
#else
    asm volatile("v_mfma_f32_16x16x16_bf16 %0, %1, %2, %0" : "+v"(c) : "v"(a), "v"(b));
    return c;
#endif
}

// Y[M=4096][N=512] = (X[M][512] @ W[N][512]^T) * scale
// OUT_MODE: 0 = bf16 row-major, 1 = bf16 transposed ([N][S_]), 2 = fp32 row-major
template<bool IN_BF16, int OUT_MODE>
__global__ __launch_bounds__(256) void proj_kernel(const void* __restrict__ Xv,
                                                   const float* __restrict__ W,
                                                   void* __restrict__ Yv, float scale) {
    constexpr int BM = 128, BN = 64, BK = 64;
    __shared__ unsigned short Xs[BM][BK + 8];
    __shared__ unsigned short Ws_[BN][BK + 8];
    const int m0 = blockIdx.x * BM;
    const int n0 = blockIdx.y * BN;
    const int tid = threadIdx.x;
    const int lane = tid & 63, w = tid >> 6;
    const int wi = w >> 1, wj = w & 1;
    const int lr = lane & 15, lg = lane >> 4;

    f32x4 acc[4][2] = {};

    for (int kt = 0; kt < D_ / BK; ++kt) {
        const int k0 = kt * BK;
        __syncthreads();
        if (IN_BF16) {
            const unsigned short* X = (const unsigned short*)Xv;
#pragma unroll
            for (int r = 0; r < 4; ++r) {
                int idx = tid + r * 256;
                int row = idx >> 3, c8 = idx & 7;
                u16x8 vv = *(const u16x8*)(X + (size_t)(m0 + row) * D_ + k0 + c8 * 8);
                *(u16x8*)&Xs[row][c8 * 8] = vv;
            }
        } else {
            const float* X = (const float*)Xv;
#pragma unroll
            for (int r = 0; r < 8; ++r) {
                int idx = tid + r * 256;
                int row = idx >> 4, c4 = idx & 15;
                f32x4 vv = *(const f32x4*)(X + (size_t)(m0 + row) * D_ + k0 + c4 * 4);
                u16x4 o;
#pragma unroll
                for (int t = 0; t < 4; ++t) o[t] = f2bf(vv[t]);
                *(u16x4*)&Xs[row][c4 * 4] = o;
            }
        }
#pragma unroll
        for (int r = 0; r < 4; ++r) {
            int idx = tid + r * 256;
            int row = idx >> 4, c4 = idx & 15;
            f32x4 vv = *(const f32x4*)(W + (size_t)(n0 + row) * D_ + k0 + c4 * 4);
            u16x4 o;
#pragma unroll
            for (int t = 0; t < 4; ++t) o[t] = f2bf(vv[t]);
            *(u16x4*)&Ws_[row][c4 * 4] = o;
        }
        __syncthreads();
#pragma unroll
        for (int ks = 0; ks < 2; ++ks) {
            s16x8 a[4], b[2];
#pragma unroll
            for (int mf = 0; mf < 4; ++mf)
                a[mf] = *(const s16x8*)&Xs[wi * 64 + mf * 16 + lr][ks * 32 + lg * 8];
#pragma unroll
            for (int nf = 0; nf < 2; ++nf)
                b[nf] = *(const s16x8*)&Ws_[wj * 32 + nf * 16 + lr][ks * 32 + lg * 8];
#pragma unroll
            for (int mf = 0; mf < 4; ++mf)
#pragma unroll
                for (int nf = 0; nf < 2; ++nf)
                    acc[mf][nf] = __builtin_amdgcn_mfma_f32_16x16x32_bf16(a[mf], b[nf], acc[mf][nf], 0, 0, 0);
        }
    }

    if (OUT_MODE == 1) {
        __syncthreads();
        unsigned short* T = &Xs[0][0] + w * 2304;   // per-wave [32][72]
#pragma unroll
        for (int mf = 0; mf < 4; ++mf)
#pragma unroll
            for (int nf = 0; nf < 2; ++nf)
#pragma unroll
                for (int r = 0; r < 4; ++r) {
                    int n_loc = nf * 16 + lr;
                    int i_loc = mf * 16 + lg * 4 + r;
                    T[n_loc * 72 + i_loc] = f2bf(acc[mf][nf][r] * scale);
                }
        __syncthreads();
        unsigned short* Y = (unsigned short*)Yv;
#pragma unroll
        for (int rr = 0; rr < 4; ++rr) {
            int chunk = lane + rr * 64;
            int n_loc = chunk >> 3, c8 = chunk & 7;
            u16x8 vv = *(const u16x8*)&T[n_loc * 72 + c8 * 8];
            *(u16x8*)(Y + (size_t)(n0 + wj * 32 + n_loc) * S_ + m0 + wi * 64 + c8 * 8) = vv;
        }
    } else {
#pragma unroll
        for (int mf = 0; mf < 4; ++mf)
#pragma unroll
            for (int nf = 0; nf < 2; ++nf)
#pragma unroll
                for (int r = 0; r < 4; ++r) {
                    int i = m0 + wi * 64 + mf * 16 + lg * 4 + r;
                    int n = n0 + wj * 32 + nf * 16 + lr;
                    float val = acc[mf][nf][r] * scale;
                    if (OUT_MODE == 0) ((unsigned short*)Yv)[(size_t)i * D_ + n] = f2bf(val);
                    else                ((float*)Yv)[(size_t)i * D_ + n] = val;
                }
    }
}

// Attention, head-axis softmax, barrier-light.
// Block = 4 waves = one team of 32 q-rows. Wave w owns heads 2w,2w+1 (k-slice
// kb=w*128). Swapped QK (mfma(K,Q)): lane holds S[j=lg*4+r][i=lr] -> softmax
// lane-local except the 8-head denominator, exchanged via LDS + raw lgkm-only
// barrier (vmem loads stay in flight). P fragment == B-operand of 16x16x16
// PV MFMA directly -> no P LDS roundtrip. Output O^T[d][i] to partial[jc][D][S].
__global__ __launch_bounds__(256, 2) void attn_kernel(const unsigned short* __restrict__ Qp,
                                                      const unsigned short* __restrict__ Kp,
                                                      const unsigned short* __restrict__ VpT,
                                                      float* __restrict__ partial) {
    __shared__ float den[2][4][2][64][4];          // [slot][wave][ifrag][lane][r] = 16 KB
    const int bid = blockIdx.x;                    // 512 blocks
    const int rank = (bid & 7) * 64 + (bid >> 3);  // XCD-contiguous
    const int jc = rank >> 7;                      // 0..3
    const int i0 = (rank & 127) * 32;
    const int tid = threadIdx.x;
    const int lane = tid & 63, w = tid >> 6;
    const int lr = lane & 15, lg = lane >> 4;
    const int kb = w * 128;                        // this wave's k-slice (heads 2w,2w+1)

    // Q fragments for the whole k-slice: [ifrag][kfrag], persistent registers
    s16x8 q[2][4];
#pragma unroll
    for (int f = 0; f < 2; ++f)
#pragma unroll
        for (int kf = 0; kf < 4; ++kf)
            q[f][kf] = *(const s16x8*)(Qp + (size_t)(i0 + f * 16 + lr) * D_ + kb + kf * 32 + lg * 8);

    f32x4 acc[8][2] = {};                          // [dfrag][ifrag]

    const int t0 = jc * (S_ / NJC / 16);
    const int t1 = t0 + (S_ / NJC / 16);

    for (int t = t0; t < t1; ++t) {
        const int j0 = t * 16;
        const int slot = t & 1;

        // ---- K fragments (4 x b128) and V fragments (8 x b64), issued together ----
        s16x4 vA[8];
#pragma unroll
        for (int df = 0; df < 8; ++df)
            vA[df] = *(const s16x4*)(VpT + (size_t)(kb + df * 16 + lr) * S_ + j0 + lg * 4);
        s16x8 kA[4];
#pragma unroll
        for (int kf = 0; kf < 4; ++kf)
            kA[kf] = *(const s16x8*)(Kp + (size_t)(j0 + lr) * D_ + kb + kf * 32 + lg * 8);

        // ---- QK^T (swapped): sf[hh][f] = S[h=2w+hh][j=lg*4+r][i=f*16+lr] ----
        f32x4 sf[2][2] = {};
#pragma unroll
        for (int hh = 0; hh < 2; ++hh)
#pragma unroll
            for (int ks = 0; ks < 2; ++ks)
#pragma unroll
                for (int f = 0; f < 2; ++f)
                    sf[hh][f] = __builtin_amdgcn_mfma_f32_16x16x32_bf16(kA[hh * 2 + ks], q[f][hh * 2 + ks], sf[hh][f], 0, 0, 0);

        // ---- exp2 (Q pre-scaled by 1/8*log2e) + local 2-head denominator ----
#pragma unroll
        for (int hh = 0; hh < 2; ++hh)
#pragma unroll
            for (int f = 0; f < 2; ++f)
#pragma unroll
                for (int r = 0; r < 4; ++r)
                    sf[hh][f][r] = exp2f(sf[hh][f][r]);
#pragma unroll
        for (int f = 0; f < 2; ++f)
            *(f32x4*)den[slot][w][f][lane] = sf[0][f] + sf[1][f];

        // raw barrier: LDS-only drain, vmem (V/K prefetch) stays in flight
        asm volatile("s_waitcnt lgkmcnt(0)\n\ts_barrier" ::: "memory");

        // ---- total denominator over all 4 waves (8 heads) ----
        f32x4 dt[2];
#pragma unroll
        for (int f = 0; f < 2; ++f) {
            dt[f] = *(const f32x4*)den[slot][0][f][lane];
#pragma unroll
            for (int wp = 1; wp < 4; ++wp)
                dt[f] += *(const f32x4*)den[slot][wp][f][lane];
        }

        // ---- normalize + pack: P fragment is directly the 16x16x16 B operand ----
        s16x4 pb[2][2];
#pragma unroll
        for (int f = 0; f < 2; ++f) {
            f32x4 rd;
#pragma unroll
            for (int r = 0; r < 4; ++r) rd[r] = __builtin_amdgcn_rcpf(dt[f][r]);
#pragma unroll
            for (int hh = 0; hh < 2; ++hh) {
                union { s16x4 v; uint2 u; } pc;
                pc.u.x = pack_bf16(sf[hh][f][0] * rd[0], sf[hh][f][1] * rd[1]);
                pc.u.y = pack_bf16(sf[hh][f][2] * rd[2], sf[hh][f][3] * rd[3]);
                pb[hh][f] = pc.v;
            }
        }

        // ---- PV: acc[df][f] += V^T[d][j16] * P[i][j16] ----
#pragma unroll
        for (int df = 0; df < 8; ++df)
#pragma unroll
            for (int f = 0; f < 2; ++f)
                acc[df][f] = mfma16(vA[df], pb[df >> 2][f], acc[df][f]);
    }

    // ---- store O^T[d][i] to partial[jc][D][S] ----
    float* P = partial + (size_t)jc * D_ * S_;
#pragma unroll
    for (int df = 0; df < 8; ++df)
#pragma unroll
        for (int f = 0; f < 2; ++f)
#pragma unroll
            for (int r = 0; r < 4; ++r)
                P[(size_t)(kb + df * 16 + lg * 4 + r) * S_ + i0 + f * 16 + lr] = acc[df][f][r];
}

// Sum NJC partials of O^T[d][i] and transpose to ao[i][d] bf16.
__global__ __launch_bounds__(256) void reduceT_kernel(const float* __restrict__ partial,
                                                      unsigned short* __restrict__ ao) {
    __shared__ float T[64][73];
    const int i0 = blockIdx.x * 64;
    const int d0 = blockIdx.y * 64;
    const int tid = threadIdx.x;
    const int dd = tid >> 2, iq = tid & 3;         // input: 64 d-rows x 4 i-quarters

    f32x4 sum[4] = {};
#pragma unroll
    for (int jc = 0; jc < NJC; ++jc) {
        const float* src = partial + (size_t)jc * D_ * S_ + (size_t)(d0 + dd) * S_ + i0 + iq * 16;
#pragma unroll
        for (int e = 0; e < 4; ++e)
            sum[e] += *(const f32x4*)(src + e * 4);
    }
#pragma unroll
    for (int e = 0; e < 4; ++e)
#pragma unroll
        for (int s = 0; s < 4; ++s)
            T[dd][iq * 16 + e * 4 + s] = sum[e][s];
    __syncthreads();

    const int ir = tid & 63, dq = tid >> 6;        // output: 64 i-rows x 4 d-quarters
    unsigned short us[16];
#pragma unroll
    for (int kk = 0; kk < 16; ++kk)
        us[kk] = f2bf(T[dq * 16 + kk][ir]);
    unsigned short* dst = ao + (size_t)(i0 + ir) * D_ + d0 + dq * 16;
    *(u16x8*)dst = *(u16x8*)&us[0];
    *(u16x8*)(dst + 8) = *(u16x8*)&us[8];
}

extern "C" void kernel_launch(void* const* d_in, const int* in_sizes, int n_in,
                              void* d_out, int out_size, void* d_ws, size_t ws_size,
                              hipStream_t stream) {
    const float* q  = (const float*)d_in[0];
    const float* k  = (const float*)d_in[1];
    const float* v  = (const float*)d_in[2];
    const float* Wq = (const float*)d_in[3];
    const float* Wk = (const float*)d_in[4];
    const float* Wv = (const float*)d_in[5];
    const float* Wo = (const float*)d_in[6];

    char* ws = (char*)d_ws;
    unsigned short* Qp  = (unsigned short*)(ws);                    // 4 MB bf16 [S][D]
    unsigned short* Kp  = (unsigned short*)(ws + (4u  << 20));      // 4 MB bf16 [S][D]
    unsigned short* VpT = (unsigned short*)(ws + (8u  << 20));      // 4 MB bf16 [D][S]
    float*          part= (float*)        (ws + (12u << 20));       // NJC * 8 MB fp32 [jc][D][S]
    unsigned short* ao  = (unsigned short*)(ws + (44u << 20));      // 4 MB bf16 [S][D]

    const float qscale = 0.125f * 1.44269504088896340736f;  // 1/8 * log2(e)

    dim3 pb(256);
    dim3 pg(S_ / 128, D_ / 64);
    proj_kernel<false, 0><<<pg, pb, 0, stream>>>(q, Wq, Qp, qscale);
    proj_kernel<false, 0><<<pg, pb, 0, stream>>>(k, Wk, Kp, 1.0f);
    proj_kernel<false, 1><<<pg, pb, 0, stream>>>(v, Wv, VpT, 1.0f);
    attn_kernel<<<dim3(128 * NJC), pb, 0, stream>>>(Qp, Kp, VpT, part);
    reduceT_kernel<<<dim3(S_ / 64, D_ / 64), pb, 0, stream>>>(part, ao);
    proj_kernel<true, 2><<<pg, pb, 0, stream>>>(ao, Wo, (float*)d_out, 1.0f);
}